// Round 3
// baseline (349.876 us; speedup 1.0000x reference)
//
#include <hip/hip_runtime.h>

typedef unsigned short u16;
typedef unsigned int   u32;

#define NB 4
#define NT 4096
#define NC 512
#define NH 64
// scores scaled by EMBED**-0.5 = 512**-0.5, folded into q at projection time
#define ATT_SCALE 0.044194173824159216f
#define NEG_BIG   -30000.0f

typedef __attribute__((ext_vector_type(8))) _Float16 half8;
typedef __attribute__((ext_vector_type(4))) float    floatx4;

// ---------------------------------------------------------------------------
// Kernel 1: q/k/v projections. Inputs fp32 (reference dtypes). 16 rows of x
// per block, staged in LDS. Outputs fp16: q (pre-scaled by ATT_SCALE),
// k row-major [B*T][H], v transposed [B][H][T] (so attention PV B-fragments
// are contiguous ds_read_b128).
// ---------------------------------------------------------------------------
__global__ __launch_bounds__(256) void qkv_proj(
    const float* __restrict__ x, const float* __restrict__ Wk,
    const float* __restrict__ Wq, const float* __restrict__ Wv,
    _Float16* __restrict__ qo, _Float16* __restrict__ ko,
    _Float16* __restrict__ vto)
{
    __shared__ __align__(16) float xs[16][516];  // +4 pad spreads banks
    const int tid = threadIdx.x;
    const int rowbase = blockIdx.x * 16;

    // stage 16 x 512 fp32 = 2048 float4, 8 per thread
#pragma unroll
    for (int i = 0; i < 8; ++i) {
        int idx = tid + 256 * i;            // 0..2047
        int r = idx >> 7, c4 = idx & 127;   // 128 float4 per row
        *(float4*)&xs[r][c4 * 4] = *(const float4*)&x[(rowbase + r) * NC + c4 * 4];
    }
    __syncthreads();

    const int h  = tid & 63;   // output column (head dim)
    const int rg = tid >> 6;   // row group: rows rg*4 .. rg*4+3 (wave-uniform -> LDS broadcast)

    for (int w = 0; w < 3; ++w) {
        const float* W = (w == 0) ? Wq : (w == 1) ? Wk : Wv;
        float acc[4] = {0.f, 0.f, 0.f, 0.f};
        for (int c = 0; c < NC; c += 8) {
            float4 w0 = *(const float4*)&W[h * NC + c];
            float4 w1 = *(const float4*)&W[h * NC + c + 4];
#pragma unroll
            for (int j = 0; j < 4; ++j) {
                float4 a0 = *(const float4*)&xs[rg * 4 + j][c];
                float4 a1 = *(const float4*)&xs[rg * 4 + j][c + 4];
                acc[j] += a0.x * w0.x + a0.y * w0.y + a0.z * w0.z + a0.w * w0.w
                        + a1.x * w1.x + a1.y * w1.y + a1.z * w1.z + a1.w * w1.w;
            }
        }
        if (w == 0) {
#pragma unroll
            for (int j = 0; j < 4; ++j)
                qo[(rowbase + rg * 4 + j) * NH + h] = (_Float16)(acc[j] * ATT_SCALE);
        } else if (w == 1) {
#pragma unroll
            for (int j = 0; j < 4; ++j)
                ko[(rowbase + rg * 4 + j) * NH + h] = (_Float16)acc[j];
        } else {
            int g = rowbase + rg * 4;
            int bb = g >> 12, t0 = g & (NT - 1);   // 16-row tile never crosses batch
            _Float16* dst = &vto[(bb * NH + h) * NT + t0];
#pragma unroll
            for (int j = 0; j < 4; ++j) dst[j] = (_Float16)acc[j];
        }
    }
}

// ---------------------------------------------------------------------------
// Kernel 2: fused causal flash attention, mfma_f32_16x16x32_f16.
// Block = 256 threads (4 waves); wave wv owns q rows [qt*64+wv*16, +16).
// A-frag layout: A[m=lane&15][k=(lane>>4)*8+j]; C/D: col=lane&15, row=quad*4+reg.
// K tile LDS row-major [s][h]; V tile LDS transposed [h][s]; both padded to 72
// halves/row (144B stride -> worst 2-way bank aliasing on b128 frag reads, free).
// P goes through per-wave LDS to convert C-layout -> A-layout (m120 pattern).
// Output fp32 (reference output dtype).
// ---------------------------------------------------------------------------
__global__ __launch_bounds__(256) void attn_fused(
    const _Float16* __restrict__ q, const _Float16* __restrict__ k,
    const _Float16* __restrict__ vt, float* __restrict__ out)
{
    constexpr int KP = 72;
    __shared__ __align__(16) _Float16 Ks[64 * KP];
    __shared__ __align__(16) _Float16 Vs[64 * KP];
    __shared__ __align__(16) _Float16 Ps[4][16 * KP];

    const int tid  = threadIdx.x;
    const int wv   = tid >> 6;
    const int lane = tid & 63;
    const int quad = lane >> 4;
    const int id   = lane & 15;
    const int qt   = blockIdx.x;
    const int b    = blockIdx.y;
    const int qrow0 = qt * 64 + wv * 16;   // wave's first q row (within batch)

    // Q A-fragments stay in registers the whole kernel (q already scaled)
    half8 qa0, qa1;
    {
        const _Float16* qp = q + (b * NT + qrow0 + id) * NH + quad * 8;
        qa0 = *(const half8*)qp;
        qa1 = *(const half8*)(qp + 32);
    }

    floatx4 o[4] = {};
    float m_i[4], l_i[4];
#pragma unroll
    for (int r = 0; r < 4; ++r) { m_i[r] = NEG_BIG; l_i[r] = 0.f; }

    for (int kt = 0; kt <= qt; ++kt) {
        const int kbase = kt * 64;
        // stage K (row-major) and V^T (row-major in transposed space)
#pragma unroll
        for (int i = 0; i < 2; ++i) {
            int idx = tid + 256 * i;       // 512 x uint4 = 2 x (64 rows x 64 halves)
            int r = idx >> 3, c8 = idx & 7;
            *(uint4*)&Ks[r * KP + c8 * 8] =
                *(const uint4*)&k[(b * NT + kbase + r) * NH + c8 * 8];
            *(uint4*)&Vs[r * KP + c8 * 8] =
                *(const uint4*)&vt[(b * NH + r) * NT + kbase + c8 * 8];
        }
        __syncthreads();

        // S[16 x 64] = Q Kt   (B-frag: B[k=h][n=s] = K[s][h], contiguous h)
        floatx4 s[4] = {};
#pragma unroll
        for (int t = 0; t < 4; ++t) {
            half8 b0 = *(const half8*)&Ks[(t * 16 + id) * KP + quad * 8];
            half8 b1 = *(const half8*)&Ks[(t * 16 + id) * KP + 32 + quad * 8];
            s[t] = __builtin_amdgcn_mfma_f32_16x16x32_f16(qa0, b0, s[t], 0, 0, 0);
            s[t] = __builtin_amdgcn_mfma_f32_16x16x32_f16(qa1, b1, s[t], 0, 0, 0);
        }

        if (kt == qt) {  // causal mask, diagonal tile only
#pragma unroll
            for (int t = 0; t < 4; ++t)
#pragma unroll
                for (int r = 0; r < 4; ++r)
                    if (kbase + t * 16 + id > qrow0 + quad * 4 + r)
                        s[t][r] = NEG_BIG;
        }

        // online softmax; row r of this lane = quad*4+r, shared by 16 lanes (same quad)
        float alpha[4];
#pragma unroll
        for (int r = 0; r < 4; ++r) {
            float mx = fmaxf(fmaxf(s[0][r], s[1][r]), fmaxf(s[2][r], s[3][r]));
            mx = fmaxf(mx, __shfl_xor(mx, 1));
            mx = fmaxf(mx, __shfl_xor(mx, 2));
            mx = fmaxf(mx, __shfl_xor(mx, 4));
            mx = fmaxf(mx, __shfl_xor(mx, 8));
            float mnew = fmaxf(m_i[r], mx);
            alpha[r] = __expf(m_i[r] - mnew);
            m_i[r] = mnew;
            float psum = 0.f;
#pragma unroll
            for (int t = 0; t < 4; ++t) {
                float p = __expf(s[t][r] - mnew);
                s[t][r] = p;
                psum += p;
            }
            psum += __shfl_xor(psum, 1);
            psum += __shfl_xor(psum, 2);
            psum += __shfl_xor(psum, 4);
            psum += __shfl_xor(psum, 8);
            l_i[r] = l_i[r] * alpha[r] + psum;
        }

        // rescale O, spill P (C-layout) to per-wave LDS as fp16
#pragma unroll
        for (int t = 0; t < 4; ++t)
#pragma unroll
            for (int r = 0; r < 4; ++r) {
                o[t][r] *= alpha[r];
                Ps[wv][(quad * 4 + r) * KP + t * 16 + id] = (_Float16)s[t][r];
            }

        __syncthreads();   // orders P write -> A-layout read (conservative)

        // O[16 x 64] += P V   (A-frag from Ps; B-frag: B[k=s][n=h] = Vs[h][s])
        half8 pa0 = *(const half8*)&Ps[wv][id * KP + quad * 8];
        half8 pa1 = *(const half8*)&Ps[wv][id * KP + 32 + quad * 8];
#pragma unroll
        for (int t = 0; t < 4; ++t) {
            half8 v0 = *(const half8*)&Vs[(t * 16 + id) * KP + quad * 8];
            half8 v1 = *(const half8*)&Vs[(t * 16 + id) * KP + 32 + quad * 8];
            o[t] = __builtin_amdgcn_mfma_f32_16x16x32_f16(pa0, v0, o[t], 0, 0, 0);
            o[t] = __builtin_amdgcn_mfma_f32_16x16x32_f16(pa1, v1, o[t], 0, 0, 0);
        }
        __syncthreads();   // all waves done reading Ks/Vs before next staging
    }

    // epilogue: out = O / l, fp32 (reference output dtype)
#pragma unroll
    for (int r = 0; r < 4; ++r) {
        float rl = 1.f / l_i[r];
#pragma unroll
        for (int t = 0; t < 4; ++t)
            out[(b * NT + qrow0 + quad * 4 + r) * NH + t * 16 + id] = o[t][r] * rl;
    }
}

extern "C" void kernel_launch(void* const* d_in, const int* in_sizes, int n_in,
                              void* d_out, int out_size, void* d_ws, size_t ws_size,
                              hipStream_t stream) {
    const float* x  = (const float*)d_in[0];
    const float* Wk = (const float*)d_in[1];
    const float* Wq = (const float*)d_in[2];
    const float* Wv = (const float*)d_in[3];

    // workspace: q, k (row-major) and vT, fp16 — 3 x 2 MB = 6 MB
    _Float16* qo  = (_Float16*)d_ws;
    _Float16* ko  = qo + NB * NT * NH;
    _Float16* vto = ko + NB * NT * NH;

    qkv_proj<<<dim3(NB * NT / 16), 256, 0, stream>>>(x, Wk, Wq, Wv, qo, ko, vto);
    attn_fused<<<dim3(NT / 64, NB), 256, 0, stream>>>(qo, ko, vto, (float*)d_out);
}

// Round 4
// 228.582 us; speedup vs baseline: 1.5306x; 1.5306x over previous
//
#include <hip/hip_runtime.h>

typedef unsigned short u16;
typedef unsigned int   u32;

#define NB 4
#define NT 4096
#define NC 512
#define NH 64
// scores scaled by EMBED**-0.5 = 512**-0.5, folded into q at projection time
#define ATT_SCALE 0.044194173824159216f
#define NEG_BIG   -30000.0f

typedef __attribute__((ext_vector_type(8))) _Float16 half8;
typedef __attribute__((ext_vector_type(4))) _Float16 half4;
typedef __attribute__((ext_vector_type(4))) float    floatx4;

// ---------------------------------------------------------------------------
// Kernel 1: q/k/v projections via MFMA. Grid = 256 blocks, 64 x-rows each.
// Per 64-k chunk: stage x (fp32->fp16) + all 3 W chunks in LDS; one x A-frag
// feeds 12 MFMAs (3 W x 4 n-tiles). Outputs fp16: q (pre-scaled), k row-major
// [B*T][H], v transposed [B][H][T].
// ---------------------------------------------------------------------------
__global__ __launch_bounds__(256) void qkv_proj(
    const float* __restrict__ x, const float* __restrict__ Wk,
    const float* __restrict__ Wq, const float* __restrict__ Wv,
    _Float16* __restrict__ qo, _Float16* __restrict__ ko,
    _Float16* __restrict__ vto)
{
    constexpr int KP = 72;                     // 64 + 8 pad (halves)
    __shared__ __align__(16) _Float16 xs[64 * KP];
    __shared__ __align__(16) _Float16 ws[3][64 * KP];

    const int tid  = threadIdx.x;
    const int wv   = tid >> 6;
    const int lane = tid & 63;
    const int quad = lane >> 4;
    const int id   = lane & 15;
    const int rowbase = blockIdx.x * 64;       // 64 divides 4096: no batch crossing

    floatx4 acc[3][4] = {};                    // [w][nt], C-layout 16x16 frags

    for (int c8 = 0; c8 < 8; ++c8) {
        const int kofs = c8 * 64;
        // stage x chunk: 64 rows x 64 fp32 -> fp16 (4 float4 per thread)
#pragma unroll
        for (int i = 0; i < 4; ++i) {
            int idx = tid + 256 * i;           // 0..1023
            int r = idx >> 4, c4 = idx & 15;
            float4 f = *(const float4*)&x[(rowbase + r) * NC + kofs + c4 * 4];
            half4 h = {(_Float16)f.x, (_Float16)f.y, (_Float16)f.z, (_Float16)f.w};
            *(half4*)&xs[r * KP + c4 * 4] = h;
        }
        // stage W chunks (64 h x 64 k each, L2-resident after first touch)
#pragma unroll
        for (int w = 0; w < 3; ++w) {
            const float* W = (w == 0) ? Wq : (w == 1) ? Wk : Wv;
#pragma unroll
            for (int i = 0; i < 4; ++i) {
                int idx = tid + 256 * i;
                int r = idx >> 4, c4 = idx & 15;
                float4 f = *(const float4*)&W[r * NC + kofs + c4 * 4];
                half4 h = {(_Float16)f.x, (_Float16)f.y, (_Float16)f.z, (_Float16)f.w};
                *(half4*)&ws[w][r * KP + c4 * 4] = h;
            }
        }
        __syncthreads();

#pragma unroll
        for (int ks = 0; ks < 2; ++ks) {
            half8 a = *(const half8*)&xs[(wv * 16 + id) * KP + ks * 32 + quad * 8];
#pragma unroll
            for (int w = 0; w < 3; ++w)
#pragma unroll
                for (int nt = 0; nt < 4; ++nt) {
                    half8 bf = *(const half8*)&ws[w][(nt * 16 + id) * KP + ks * 32 + quad * 8];
                    acc[w][nt] = __builtin_amdgcn_mfma_f32_16x16x32_f16(a, bf, acc[w][nt], 0, 0, 0);
                }
        }
        __syncthreads();                       // before next chunk overwrites LDS
    }

    // epilogue: C/D layout col=id (h within nt), row=quad*4+r (x-row in wave strip)
#pragma unroll
    for (int nt = 0; nt < 4; ++nt) {
        int h = nt * 16 + id;
#pragma unroll
        for (int r = 0; r < 4; ++r) {
            int rowg = rowbase + wv * 16 + quad * 4 + r;
            qo[rowg * NH + h] = (_Float16)(acc[0][nt][r] * ATT_SCALE);
            ko[rowg * NH + h] = (_Float16)acc[1][nt][r];
            int bb = rowg >> 12, t0 = rowg & (NT - 1);
            vto[(bb * NH + h) * NT + t0] = (_Float16)acc[2][nt][r];
        }
    }
}

// ---------------------------------------------------------------------------
// Kernel 2: transposed flash attention. S^T = K Q^T and O^T = V^T P^T
// (operand-swapped MFMAs): each lane owns one q-row (q = lane&15), so the
// softmax reduce is in-lane(16) + 2 shuffles (xor 16/32) and m/l/alpha are
// per-lane scalars — no broadcasts anywhere. K/V double-buffered with
// register prefetch; ONE barrier per k-tile (P LDS round-trip is wave-private,
// ordered by lgkmcnt). Output fp32, float4 stores.
// ---------------------------------------------------------------------------
__global__ __launch_bounds__(256) void attn_fused(
    const _Float16* __restrict__ q, const _Float16* __restrict__ k,
    const _Float16* __restrict__ vt, float* __restrict__ out)
{
    constexpr int KP = 72;
    __shared__ __align__(16) _Float16 Ks[2][64 * KP];
    __shared__ __align__(16) _Float16 Vs[2][64 * KP];
    __shared__ __align__(16) _Float16 Ps[4][16 * KP];

    const int tid  = threadIdx.x;
    const int wv   = tid >> 6;
    const int lane = tid & 63;
    const int quad = lane >> 4;
    const int id   = lane & 15;
    const int qt   = blockIdx.x;
    const int b    = blockIdx.y;
    const int qrow0 = qt * 64 + wv * 16;
    const int qglob = qrow0 + id;              // this lane's q row (within batch)

    // Q fragment: same registers as before, now used as the B operand of S^T
    half8 qb0, qb1;
    {
        const _Float16* qp = q + (b * NT + qglob) * NH + quad * 8;
        qb0 = *(const half8*)qp;
        qb1 = *(const half8*)(qp + 32);
    }

    floatx4 o[4] = {};                         // O^T frags: o[t][r] = O[h=16t+quad*4+r][q=id]
    float m_i = NEG_BIG, l_i = 0.f;

    // prologue: stage kt=0 into buffer 0
#pragma unroll
    for (int i = 0; i < 2; ++i) {
        int idx = tid + 256 * i;               // 0..511
        int r = idx >> 3, c8 = idx & 7;
        *(uint4*)&Ks[0][r * KP + c8 * 8] = *(const uint4*)&k[(b * NT + r) * NH + c8 * 8];
        *(uint4*)&Vs[0][r * KP + c8 * 8] = *(const uint4*)&vt[(b * NH + r) * NT + c8 * 8];
    }
    __syncthreads();

    for (int kt = 0; kt <= qt; ++kt) {
        const int cur   = kt & 1;
        const int kbase = kt * 64;
        const bool pf   = (kt < qt);

        // prefetch next K/V tile into registers (drains during compute)
        uint4 pk[2], pv[2];
        if (pf) {
            const int nb = kbase + 64;
#pragma unroll
            for (int i = 0; i < 2; ++i) {
                int idx = tid + 256 * i;
                int r = idx >> 3, c8 = idx & 7;
                pk[i] = *(const uint4*)&k[(b * NT + nb + r) * NH + c8 * 8];
                pv[i] = *(const uint4*)&vt[(b * NH + r) * NT + nb + c8 * 8];
            }
        }

        // S^T[64k x 16q]: A = K frag (same LDS reads as B-role before), B = Q
        floatx4 s[4] = {};
#pragma unroll
        for (int t = 0; t < 4; ++t) {
            half8 ka0 = *(const half8*)&Ks[cur][(t * 16 + id) * KP + quad * 8];
            half8 ka1 = *(const half8*)&Ks[cur][(t * 16 + id) * KP + 32 + quad * 8];
            s[t] = __builtin_amdgcn_mfma_f32_16x16x32_f16(ka0, qb0, s[t], 0, 0, 0);
            s[t] = __builtin_amdgcn_mfma_f32_16x16x32_f16(ka1, qb1, s[t], 0, 0, 0);
        }

        if (kt == qt) {                        // causal mask: k = kbase+16t+quad*4+r
#pragma unroll
            for (int t = 0; t < 4; ++t)
#pragma unroll
                for (int r = 0; r < 4; ++r)
                    if (kbase + 16 * t + quad * 4 + r > qglob)
                        s[t][r] = NEG_BIG;
        }

        // online softmax over k: in-lane 16 + cross-quad (2 shuffles each)
        float mx = s[0][0];
#pragma unroll
        for (int t = 0; t < 4; ++t)
#pragma unroll
            for (int r = 0; r < 4; ++r) mx = fmaxf(mx, s[t][r]);
        mx = fmaxf(mx, __shfl_xor(mx, 16));
        mx = fmaxf(mx, __shfl_xor(mx, 32));
        float mnew  = fmaxf(m_i, mx);
        float alpha = __expf(m_i - mnew);
        m_i = mnew;
        float psum = 0.f;
#pragma unroll
        for (int t = 0; t < 4; ++t)
#pragma unroll
            for (int r = 0; r < 4; ++r) {
                float p = __expf(s[t][r] - mnew);
                s[t][r] = p;
                psum += p;
            }
        psum += __shfl_xor(psum, 16);
        psum += __shfl_xor(psum, 32);
        l_i = l_i * alpha + psum;

        // spill P^T as P[q=id][k] — 4 packed b64 writes (r-values contiguous)
#pragma unroll
        for (int t = 0; t < 4; ++t) {
            half4 ph = {(_Float16)s[t][0], (_Float16)s[t][1],
                        (_Float16)s[t][2], (_Float16)s[t][3]};
            *(half4*)&Ps[wv][id * KP + 16 * t + quad * 4] = ph;
        }

        // rescale O^T (alpha is per-lane — no broadcast)
#pragma unroll
        for (int t = 0; t < 4; ++t)
#pragma unroll
            for (int r = 0; r < 4; ++r) o[t][r] *= alpha;

        // wave-private LDS round trip; lgkmcnt orders write->read
        half8 pb0 = *(const half8*)&Ps[wv][id * KP + quad * 8];
        half8 pb1 = *(const half8*)&Ps[wv][id * KP + 32 + quad * 8];

        // O^T += V^T P^T: A = V frag (same LDS reads as before), B = P
#pragma unroll
        for (int t = 0; t < 4; ++t) {
            half8 va0 = *(const half8*)&Vs[cur][(t * 16 + id) * KP + quad * 8];
            half8 va1 = *(const half8*)&Vs[cur][(t * 16 + id) * KP + 32 + quad * 8];
            o[t] = __builtin_amdgcn_mfma_f32_16x16x32_f16(va0, pb0, o[t], 0, 0, 0);
            o[t] = __builtin_amdgcn_mfma_f32_16x16x32_f16(va1, pb1, o[t], 0, 0, 0);
        }

        // commit prefetched tile to the other buffer, then the single barrier
        if (pf) {
#pragma unroll
            for (int i = 0; i < 2; ++i) {
                int idx = tid + 256 * i;
                int r = idx >> 3, c8 = idx & 7;
                *(uint4*)&Ks[cur ^ 1][r * KP + c8 * 8] = pk[i];
                *(uint4*)&Vs[cur ^ 1][r * KP + c8 * 8] = pv[i];
            }
        }
        __syncthreads();
    }

    // epilogue: out[q][h] fp32; o[t] covers h = 16t+quad*4..+3 (contiguous) -> float4
    float rl = 1.f / l_i;
#pragma unroll
    for (int t = 0; t < 4; ++t) {
        floatx4 v = o[t] * rl;
        *(float4*)&out[(b * NT + qglob) * NH + 16 * t + quad * 4] =
            make_float4(v[0], v[1], v[2], v[3]);
    }
}

extern "C" void kernel_launch(void* const* d_in, const int* in_sizes, int n_in,
                              void* d_out, int out_size, void* d_ws, size_t ws_size,
                              hipStream_t stream) {
    const float* x  = (const float*)d_in[0];
    const float* Wk = (const float*)d_in[1];
    const float* Wq = (const float*)d_in[2];
    const float* Wv = (const float*)d_in[3];

    // workspace: q, k (row-major) and vT, fp16 — 3 x 2 MB = 6 MB
    _Float16* qo  = (_Float16*)d_ws;
    _Float16* ko  = qo + NB * NT * NH;
    _Float16* vto = ko + NB * NT * NH;

    qkv_proj<<<dim3(NB * NT / 64), 256, 0, stream>>>(x, Wk, Wq, Wv, qo, ko, vto);
    attn_fused<<<dim3(NT / 64, NB), 256, 0, stream>>>(qo, ko, vto, (float*)d_out);
}

// Round 5
// 195.456 us; speedup vs baseline: 1.7901x; 1.1695x over previous
//
#include <hip/hip_runtime.h>

typedef unsigned short u16;
typedef unsigned int   u32;

#define NB 4
#define NT 4096
#define NC 512
#define NH 64
// scores scaled by EMBED**-0.5 = 512**-0.5, folded into Wq at convert time
#define ATT_SCALE 0.044194173824159216f
#define NEG_BIG   -30000.0f
#define SEG 8          // k-tiles (64 keys each) per attention partial block

typedef __attribute__((ext_vector_type(8))) _Float16 half8;
typedef __attribute__((ext_vector_type(4))) _Float16 half4;
typedef __attribute__((ext_vector_type(4))) float    floatx4;

// ---------------------------------------------------------------------------
// Kernel 0: convert W (fp32) -> Wh (fp16), [w][h][512]; w: 0=q(scaled),1=k,2=v
// ---------------------------------------------------------------------------
__global__ __launch_bounds__(256) void wconv(
    const float* __restrict__ Wk, const float* __restrict__ Wq,
    const float* __restrict__ Wv, _Float16* __restrict__ Wh)
{
    const int gid = blockIdx.x * 256 + threadIdx.x;   // 0..24575, 8192 float4 per W
    const int w = gid >> 13;
    const int i = gid & 8191;
    const float* src = (w == 0) ? Wq : (w == 1) ? Wk : Wv;
    const float sc = (w == 0) ? ATT_SCALE : 1.0f;
    float4 f = *(const float4*)&src[i * 4];
    half4 h = {(_Float16)(f.x * sc), (_Float16)(f.y * sc),
               (_Float16)(f.z * sc), (_Float16)(f.w * sc)};
    *(half4*)&Wh[w * (NH * NC) + i * 4] = h;
}

// ---------------------------------------------------------------------------
// Kernel 1: q/k/v projection GEMM — no LDS, no barriers. Each wave owns 16
// x-rows; A-frags from x fp32 (converted in-register), B-frags direct from
// fp16 Wh (L2-resident). 12 MFMAs per 32-k chunk. Outputs fp16: q (scaled),
// k row-major [B*T][H], v transposed [B][H][T].
// ---------------------------------------------------------------------------
__global__ __launch_bounds__(256) void qkv_mfma(
    const float* __restrict__ x, const _Float16* __restrict__ Wh,
    _Float16* __restrict__ qo, _Float16* __restrict__ ko,
    _Float16* __restrict__ vto)
{
    const int tid  = threadIdx.x;
    const int wv   = tid >> 6;
    const int lane = tid & 63;
    const int quad = lane >> 4;
    const int id   = lane & 15;
    const int rowbase = (blockIdx.x * 4 + wv) * 16;   // 16 rows per wave

    floatx4 acc[3][4] = {};
    const float* xp = x + (size_t)(rowbase + id) * NC;

#pragma unroll 4
    for (int ks = 0; ks < 16; ++ks) {
        float4 f0 = *(const float4*)&xp[ks * 32 + quad * 8];
        float4 f1 = *(const float4*)&xp[ks * 32 + quad * 8 + 4];
        half8 a;
        a[0] = (_Float16)f0.x; a[1] = (_Float16)f0.y;
        a[2] = (_Float16)f0.z; a[3] = (_Float16)f0.w;
        a[4] = (_Float16)f1.x; a[5] = (_Float16)f1.y;
        a[6] = (_Float16)f1.z; a[7] = (_Float16)f1.w;
#pragma unroll
        for (int w = 0; w < 3; ++w)
#pragma unroll
            for (int nt = 0; nt < 4; ++nt) {
                half8 bf = *(const half8*)&Wh[(w * NH + nt * 16 + id) * NC + ks * 32 + quad * 8];
                acc[w][nt] = __builtin_amdgcn_mfma_f32_16x16x32_f16(a, bf, acc[w][nt], 0, 0, 0);
            }
    }

    // C/D layout: col=id -> h within nt; row=quad*4+r -> x-row in wave strip
#pragma unroll
    for (int nt = 0; nt < 4; ++nt) {
        const int h  = nt * 16 + id;
        const int bb = rowbase >> 12;
        const int t0 = (rowbase & (NT - 1)) + quad * 4;
        half4 vh = {(_Float16)acc[2][nt][0], (_Float16)acc[2][nt][1],
                    (_Float16)acc[2][nt][2], (_Float16)acc[2][nt][3]};
        *(half4*)&vto[(bb * NH + h) * NT + t0] = vh;
#pragma unroll
        for (int r = 0; r < 4; ++r) {
            const int rowg = rowbase + quad * 4 + r;
            qo[rowg * NH + h] = (_Float16)acc[0][nt][r];
            ko[rowg * NH + h] = (_Float16)acc[1][nt][r];
        }
    }
}

// ---------------------------------------------------------------------------
// Kernel 2: attention partials, flash-decoding split-K. Block = 64 q-rows
// (4 waves x 16) x one segment of <=8 k-tiles. Transposed formulation
// (S^T = K Q^T, O^T = V^T P^T): per-lane softmax state, 2 shuffles/reduce.
// Single-buffered LDS (27.6 KB -> 5 blocks/CU) + register prefetch.
// Emits (m, l, unnormalized O) per (b, qt, seg).
// ---------------------------------------------------------------------------
__global__ __launch_bounds__(256) void attn_part(
    const _Float16* __restrict__ q, const _Float16* __restrict__ k,
    const _Float16* __restrict__ vt, _Float16* __restrict__ Opart,
    float* __restrict__ Mpart, float* __restrict__ Lpart)
{
    constexpr int KP = 72;
    __shared__ __align__(16) _Float16 Ks[64 * KP];
    __shared__ __align__(16) _Float16 Vs[64 * KP];
    __shared__ __align__(16) _Float16 Ps[4][16 * KP];

    const int tid  = threadIdx.x;
    const int wv   = tid >> 6;
    const int lane = tid & 63;
    const int quad = lane >> 4;
    const int id   = lane & 15;
    const int qt   = blockIdx.x;
    const int seg  = blockIdx.y;
    const int b    = blockIdx.z;
    if (seg * SEG > qt) return;                 // block-uniform; no barrier executed
    const int jbeg = seg * SEG;
    const int jend = (jbeg + SEG < qt + 1) ? jbeg + SEG : qt + 1;

    const int qglob = qt * 64 + wv * 16 + id;   // this lane's q row (within batch)

    half8 qb0, qb1;
    {
        const _Float16* qp = q + (b * NT + qglob) * NH + quad * 8;
        qb0 = *(const half8*)qp;
        qb1 = *(const half8*)(qp + 32);
    }

    floatx4 o[4] = {};
    float m_i = NEG_BIG, l_i = 0.f;

    // prologue: load first tile into registers
    uint4 pk[2], pv[2];
    {
        const int kb = jbeg * 64;
#pragma unroll
        for (int i = 0; i < 2; ++i) {
            int idx = tid + 256 * i;
            int r = idx >> 3, c = idx & 7;
            pk[i] = *(const uint4*)&k[(b * NT + kb + r) * NH + c * 8];
            pv[i] = *(const uint4*)&vt[(b * NH + r) * NT + kb + c * 8];
        }
    }

    for (int j = jbeg; j < jend; ++j) {
        // commit staged registers to LDS
#pragma unroll
        for (int i = 0; i < 2; ++i) {
            int idx = tid + 256 * i;
            int r = idx >> 3, c = idx & 7;
            *(uint4*)&Ks[r * KP + c * 8] = pk[i];
            *(uint4*)&Vs[r * KP + c * 8] = pv[i];
        }
        __syncthreads();

        // prefetch next tile (overlaps compute below)
        if (j + 1 < jend) {
            const int nb = (j + 1) * 64;
#pragma unroll
            for (int i = 0; i < 2; ++i) {
                int idx = tid + 256 * i;
                int r = idx >> 3, c = idx & 7;
                pk[i] = *(const uint4*)&k[(b * NT + nb + r) * NH + c * 8];
                pv[i] = *(const uint4*)&vt[(b * NH + r) * NT + nb + c * 8];
            }
        }

        // S^T[64k x 16q]: A = K frag, B = Q frag
        floatx4 s[4] = {};
#pragma unroll
        for (int t = 0; t < 4; ++t) {
            half8 ka0 = *(const half8*)&Ks[(t * 16 + id) * KP + quad * 8];
            half8 ka1 = *(const half8*)&Ks[(t * 16 + id) * KP + 32 + quad * 8];
            s[t] = __builtin_amdgcn_mfma_f32_16x16x32_f16(ka0, qb0, s[t], 0, 0, 0);
            s[t] = __builtin_amdgcn_mfma_f32_16x16x32_f16(ka1, qb1, s[t], 0, 0, 0);
        }

        if (j == qt) {                          // causal mask: diagonal tile only
            const int kbase = j * 64;
#pragma unroll
            for (int t = 0; t < 4; ++t)
#pragma unroll
                for (int r = 0; r < 4; ++r)
                    if (kbase + 16 * t + quad * 4 + r > qglob)
                        s[t][r] = NEG_BIG;
        }

        // online softmax over k: in-lane(16) + 2 shuffles
        float mx = s[0][0];
#pragma unroll
        for (int t = 0; t < 4; ++t)
#pragma unroll
            for (int r = 0; r < 4; ++r) mx = fmaxf(mx, s[t][r]);
        mx = fmaxf(mx, __shfl_xor(mx, 16));
        mx = fmaxf(mx, __shfl_xor(mx, 32));
        float mnew  = fmaxf(m_i, mx);
        float alpha = __expf(m_i - mnew);
        m_i = mnew;
        float psum = 0.f;
#pragma unroll
        for (int t = 0; t < 4; ++t)
#pragma unroll
            for (int r = 0; r < 4; ++r) {
                float p = __expf(s[t][r] - mnew);
                s[t][r] = p;
                psum += p;
            }
        psum += __shfl_xor(psum, 16);
        psum += __shfl_xor(psum, 32);
        l_i = l_i * alpha + psum;

        // spill P^T as P[q=id][k] — packed b64 writes
#pragma unroll
        for (int t = 0; t < 4; ++t) {
            half4 ph = {(_Float16)s[t][0], (_Float16)s[t][1],
                        (_Float16)s[t][2], (_Float16)s[t][3]};
            *(half4*)&Ps[wv][id * KP + 16 * t + quad * 4] = ph;
        }

#pragma unroll
        for (int t = 0; t < 4; ++t)
#pragma unroll
            for (int r = 0; r < 4; ++r) o[t][r] *= alpha;

        // wave-private LDS round trip (lgkmcnt orders write->read)
        half8 pb0 = *(const half8*)&Ps[wv][id * KP + quad * 8];
        half8 pb1 = *(const half8*)&Ps[wv][id * KP + 32 + quad * 8];

        // O^T += V^T P^T
#pragma unroll
        for (int t = 0; t < 4; ++t) {
            half8 va0 = *(const half8*)&Vs[(t * 16 + id) * KP + quad * 8];
            half8 va1 = *(const half8*)&Vs[(t * 16 + id) * KP + 32 + quad * 8];
            o[t] = __builtin_amdgcn_mfma_f32_16x16x32_f16(va0, pb0, o[t], 0, 0, 0);
            o[t] = __builtin_amdgcn_mfma_f32_16x16x32_f16(va1, pb1, o[t], 0, 0, 0);
        }
        __syncthreads();                        // before next commit overwrites LDS
    }

    // epilogue: write partial (m, l, unnormalized O) for this (b, qt, seg)
    const int p  = (b * 64 + qt) * SEG + seg;
    const int qr = wv * 16 + id;
#pragma unroll
    for (int t = 0; t < 4; ++t) {
        half4 oh = {(_Float16)o[t][0], (_Float16)o[t][1],
                    (_Float16)o[t][2], (_Float16)o[t][3]};
        *(half4*)&Opart[(size_t)(p * 64 + qr) * 64 + 16 * t + quad * 4] = oh;
    }
    if (quad == 0) {
        Mpart[p * 64 + qr] = m_i;
        Lpart[p * 64 + qr] = l_i;
    }
}

// ---------------------------------------------------------------------------
// Kernel 3: combine segment partials. Block per (qt, b); thread = (row, h/16).
// out = sum_s e^{m_s - M} O_s / sum_s l_s e^{m_s - M}
// ---------------------------------------------------------------------------
__global__ __launch_bounds__(256) void attn_combine(
    const _Float16* __restrict__ Opart, const float* __restrict__ Mpart,
    const float* __restrict__ Lpart, float* __restrict__ out)
{
    const int qt = blockIdx.x, b = blockIdx.y;
    const int tid = threadIdx.x;
    const int row = tid >> 2, hq = tid & 3;
    const int nseg = qt / SEG + 1;
    const int pbase = (b * 64 + qt) * SEG;

    float m[SEG];
    float M = NEG_BIG;
    for (int s = 0; s < nseg; ++s) {
        m[s] = Mpart[(pbase + s) * 64 + row];
        M = fmaxf(M, m[s]);
    }
    float L = 0.f;
    float acc[16] = {};
    for (int s = 0; s < nseg; ++s) {
        float w = __expf(m[s] - M);
        L += Lpart[(pbase + s) * 64 + row] * w;
        const _Float16* op = Opart + (size_t)((pbase + s) * 64 + row) * 64 + hq * 16;
        half8 h0 = *(const half8*)op;
        half8 h1 = *(const half8*)(op + 8);
#pragma unroll
        for (int jj = 0; jj < 8; ++jj) {
            acc[jj]     += w * (float)h0[jj];
            acc[8 + jj] += w * (float)h1[jj];
        }
    }
    const float rl = 1.f / L;
    float* dst = out + (size_t)(b * NT + qt * 64 + row) * NH + hq * 16;
#pragma unroll
    for (int jj = 0; jj < 16; ++jj) dst[jj] = acc[jj] * rl;
}

extern "C" void kernel_launch(void* const* d_in, const int* in_sizes, int n_in,
                              void* d_out, int out_size, void* d_ws, size_t ws_size,
                              hipStream_t stream) {
    const float* x  = (const float*)d_in[0];
    const float* Wk = (const float*)d_in[1];
    const float* Wq = (const float*)d_in[2];
    const float* Wv = (const float*)d_in[3];

    // ws layout (24.3 MB total):
    //   qo/ko/vto fp16: 3 x 1,048,576            = 6,291,456 B
    //   Wh fp16: 3*64*512 = 98,304               =   196,608 B
    //   Mpart/Lpart fp32: 2 x 131,072            = 1,048,576 B
    //   Opart fp16: 4*64*8*64*64 = 8,388,608     = 16,777,216 B
    char* wsb = (char*)d_ws;
    _Float16* qo    = (_Float16*)wsb;
    _Float16* ko    = qo + 1048576;
    _Float16* vto   = ko + 1048576;
    _Float16* Wh    = vto + 1048576;
    float*    Mpart = (float*)(wsb + 6488064);
    float*    Lpart = Mpart + 131072;
    _Float16* Opart = (_Float16*)(Lpart + 131072);

    wconv<<<96, 256, 0, stream>>>(Wk, Wq, Wv, Wh);
    qkv_mfma<<<NB * NT / 64, 256, 0, stream>>>(x, Wh, qo, ko, vto);
    attn_part<<<dim3(64, SEG, NB), 256, 0, stream>>>(qo, ko, vto, Opart, Mpart, Lpart);
    attn_combine<<<dim3(64, NB), 256, 0, stream>>>(Opart, Mpart, Lpart, (float*)d_out);
}

// Round 6
// 172.828 us; speedup vs baseline: 2.0244x; 1.1309x over previous
//
#include <hip/hip_runtime.h>

typedef unsigned short u16;
typedef unsigned int   u32;

#define NB 4
#define NT 4096
#define NC 512
#define NH 64
// scores scaled by EMBED**-0.5 = 512**-0.5, folded into Wq at convert time
#define ATT_SCALE 0.044194173824159216f
#define NEG_BIG   -30000.0f
#define ITEMS_PB  800      // attention work items per batch (see decode math)

typedef __attribute__((ext_vector_type(8))) _Float16 half8;
typedef __attribute__((ext_vector_type(4))) _Float16 half4;
typedef __attribute__((ext_vector_type(4))) float    floatx4;

// ---------------------------------------------------------------------------
// Kernel 0: convert W (fp32) -> Wh (fp16), [w][h][512]; w: 0=q(scaled),1=k,2=v
// ---------------------------------------------------------------------------
__global__ __launch_bounds__(256) void wconv(
    const float* __restrict__ Wk, const float* __restrict__ Wq,
    const float* __restrict__ Wv, _Float16* __restrict__ Wh)
{
    const int gid = blockIdx.x * 256 + threadIdx.x;   // 0..24575, 8192 float4 per W
    const int w = gid >> 13;
    const int i = gid & 8191;
    const float* src = (w == 0) ? Wq : (w == 1) ? Wk : Wv;
    const float sc = (w == 0) ? ATT_SCALE : 1.0f;
    float4 f = *(const float4*)&src[i * 4];
    half4 h = {(_Float16)(f.x * sc), (_Float16)(f.y * sc),
               (_Float16)(f.z * sc), (_Float16)(f.w * sc)};
    *(half4*)&Wh[w * (NH * NC) + i * 4] = h;
}

// ---------------------------------------------------------------------------
// Kernel 1: q/k/v projection GEMM, 4-way k-split. Block = 4 waves over the
// SAME 16 x-rows; wave wv handles k in [wv*128, wv*128+128). Partial fp32
// accs reduced through LDS; wave 0 writes the epilogue. Grid 1024 blocks
// -> 16 waves/CU (vs 4 before). No barriers in the k-loop.
// ---------------------------------------------------------------------------
__global__ __launch_bounds__(256) void qkv_mfma(
    const float* __restrict__ x, const _Float16* __restrict__ Wh,
    _Float16* __restrict__ qo, _Float16* __restrict__ ko,
    _Float16* __restrict__ vto)
{
    __shared__ __align__(16) floatx4 red[36][64];     // [frag(w*4+nt)*3+(wv-1)][lane]

    const int tid  = threadIdx.x;
    const int wv   = tid >> 6;
    const int lane = tid & 63;
    const int quad = lane >> 4;
    const int id   = lane & 15;
    const int rowbase = blockIdx.x * 16;

    floatx4 acc[3][4] = {};
    const float* xp = x + (size_t)(rowbase + id) * NC + wv * 128;

#pragma unroll
    for (int ks = 0; ks < 4; ++ks) {
        float4 f0 = *(const float4*)&xp[ks * 32 + quad * 8];
        float4 f1 = *(const float4*)&xp[ks * 32 + quad * 8 + 4];
        half8 a;
        a[0] = (_Float16)f0.x; a[1] = (_Float16)f0.y;
        a[2] = (_Float16)f0.z; a[3] = (_Float16)f0.w;
        a[4] = (_Float16)f1.x; a[5] = (_Float16)f1.y;
        a[6] = (_Float16)f1.z; a[7] = (_Float16)f1.w;
#pragma unroll
        for (int w = 0; w < 3; ++w)
#pragma unroll
            for (int nt = 0; nt < 4; ++nt) {
                half8 bf = *(const half8*)&Wh[(w * NH + nt * 16 + id) * NC
                                              + wv * 128 + ks * 32 + quad * 8];
                acc[w][nt] = __builtin_amdgcn_mfma_f32_16x16x32_f16(a, bf, acc[w][nt], 0, 0, 0);
            }
    }

    if (wv != 0) {
#pragma unroll
        for (int w = 0; w < 3; ++w)
#pragma unroll
            for (int nt = 0; nt < 4; ++nt)
                red[(w * 4 + nt) * 3 + (wv - 1)][lane] = acc[w][nt];
    }
    __syncthreads();
    if (wv != 0) return;

#pragma unroll
    for (int w = 0; w < 3; ++w)
#pragma unroll
        for (int nt = 0; nt < 4; ++nt)
#pragma unroll
            for (int j = 0; j < 3; ++j)
                acc[w][nt] += red[(w * 4 + nt) * 3 + j][lane];

    // C/D layout: col=id (h within nt), row=quad*4+r (x-row in the 16-strip)
    const int bb = rowbase >> 12;
    const int t0 = (rowbase & (NT - 1)) + quad * 4;
#pragma unroll
    for (int nt = 0; nt < 4; ++nt) {
        const int h = nt * 16 + id;
        half4 vh = {(_Float16)acc[2][nt][0], (_Float16)acc[2][nt][1],
                    (_Float16)acc[2][nt][2], (_Float16)acc[2][nt][3]};
        *(half4*)&vto[(bb * NH + h) * NT + t0] = vh;
#pragma unroll
        for (int r = 0; r < 4; ++r) {
            const int rowg = rowbase + quad * 4 + r;
            qo[rowg * NH + h] = (_Float16)acc[0][nt][r];
            ko[rowg * NH + h] = (_Float16)acc[1][nt][r];
        }
    }
}

// ---------------------------------------------------------------------------
// Kernel 2: attention partials — barrier-free, wave-independent flash.
// Each WAVE = one item (b, qs, seg): 32 q-rows (2 strips of 16 sharing every
// K/V fragment) x a slice of k-tiles. K/V frags loaded straight from L2
// (no K/V LDS, no __syncthreads). Only P goes through wave-private LDS
// (C-layout -> B-layout, lgkmcnt-ordered). nseg(qs) = min(qs/8+1, 8);
// item decode is closed-form. Emits normalized O-hat (fp16) + (m,l).
// ---------------------------------------------------------------------------
__global__ __launch_bounds__(256) void attn_part(
    const _Float16* __restrict__ q, const _Float16* __restrict__ k,
    const _Float16* __restrict__ vt, _Float16* __restrict__ Opart,
    float2* __restrict__ MLpart)
{
    constexpr int KP = 72;
    __shared__ __align__(16) _Float16 Ps[4][2][16 * KP];   // 18.4 KB

    const int tid  = threadIdx.x;
    const int wv   = tid >> 6;
    const int lane = tid & 63;
    const int quad = lane >> 4;
    const int id   = lane & 15;
    const int item = blockIdx.x * 4 + wv;      // [0, 800)
    const int b    = blockIdx.y;

    // decode item -> (qs, seg). Groups g = qs>>3; nseg = min(g+1, 8).
    // g<8: group g starts at 4g(g+1), 8(g+1) items. g>=8: 288 + 64(g-8), 64 items.
    int g, rem, nseg;
    if (item < 288) {
        g = (int)((__builtin_sqrtf((float)item + 1.0f) - 1.0f) * 0.5f);
        while (4 * (g + 1) * (g + 2) <= item) ++g;
        while (g > 0 && 4 * g * (g + 1) > item) --g;
        nseg = g + 1;
        rem  = item - 4 * g * (g + 1);
    } else {
        int t = item - 288;
        g    = 8 + (t >> 6);
        rem  = t & 63;
        nseg = 8;
    }
    const int qs     = 8 * g + rem / nseg;
    const int seg    = rem % nseg;
    const int ntiles = (qs >> 1) + 1;          // causal k-tiles for this strip
    const int t0 = seg * ntiles / nseg;
    const int t1 = (seg + 1) * ntiles / nseg;  // t0 < t1 guaranteed (ntiles >= nseg)

    // Q B-frags for both strips (q pre-scaled by ATT_SCALE)
    half8 qb[2][2];
#pragma unroll
    for (int s = 0; s < 2; ++s) {
        const _Float16* qp = q + (size_t)(b * NT + qs * 32 + s * 16 + id) * NH + quad * 8;
        qb[s][0] = *(const half8*)qp;
        qb[s][1] = *(const half8*)(qp + 32);
    }

    floatx4 o[2][4] = {};
    float m_i[2] = {NEG_BIG, NEG_BIG}, l_i[2] = {0.f, 0.f};

    for (int kt = t0; kt < t1; ++kt) {
        const int kb = kt * 64;

        // K A-frags straight from L2: 8 x half8 (16 B/lane, coalesced)
        half8 ka[4][2];
#pragma unroll
        for (int t = 0; t < 4; ++t) {
            const _Float16* kp = k + (size_t)(b * NT + kb + 16 * t + id) * NH + quad * 8;
            ka[t][0] = *(const half8*)kp;
            ka[t][1] = *(const half8*)(kp + 32);
        }

        // S^T[64k x 16q] per strip — K frags shared by both strips
        floatx4 s4[2][4] = {};
#pragma unroll
        for (int t = 0; t < 4; ++t)
#pragma unroll
            for (int h2 = 0; h2 < 2; ++h2) {
                s4[0][t] = __builtin_amdgcn_mfma_f32_16x16x32_f16(ka[t][h2], qb[0][h2], s4[0][t], 0, 0, 0);
                s4[1][t] = __builtin_amdgcn_mfma_f32_16x16x32_f16(ka[t][h2], qb[1][h2], s4[1][t], 0, 0, 0);
            }

        if (kt == ntiles - 1) {                // diagonal tile: causal mask
#pragma unroll
            for (int s = 0; s < 2; ++s) {
                const int qrow = qs * 32 + s * 16 + id;
#pragma unroll
                for (int t = 0; t < 4; ++t)
#pragma unroll
                    for (int r = 0; r < 4; ++r)
                        if (kb + 16 * t + quad * 4 + r > qrow)
                            s4[s][t][r] = NEG_BIG;
            }
        }

        // online softmax per strip: in-lane(16) + 2 shuffles
#pragma unroll
        for (int s = 0; s < 2; ++s) {
            float mx = s4[s][0][0];
#pragma unroll
            for (int t = 0; t < 4; ++t)
#pragma unroll
                for (int r = 0; r < 4; ++r) mx = fmaxf(mx, s4[s][t][r]);
            mx = fmaxf(mx, __shfl_xor(mx, 16));
            mx = fmaxf(mx, __shfl_xor(mx, 32));
            float mnew  = fmaxf(m_i[s], mx);
            float alpha = __expf(m_i[s] - mnew);
            m_i[s] = mnew;
            float psum = 0.f;
#pragma unroll
            for (int t = 0; t < 4; ++t)
#pragma unroll
                for (int r = 0; r < 4; ++r) {
                    float p = __expf(s4[s][t][r] - mnew);
                    s4[s][t][r] = p;
                    psum += p;
                }
            psum += __shfl_xor(psum, 16);
            psum += __shfl_xor(psum, 32);
            l_i[s] = l_i[s] * alpha + psum;

            // spill P[q=id][k] (packed b64), rescale O
#pragma unroll
            for (int t = 0; t < 4; ++t) {
                half4 ph = {(_Float16)s4[s][t][0], (_Float16)s4[s][t][1],
                            (_Float16)s4[s][t][2], (_Float16)s4[s][t][3]};
                *(half4*)&Ps[wv][s][id * KP + 16 * t + quad * 4] = ph;
            }
#pragma unroll
            for (int t = 0; t < 4; ++t)
#pragma unroll
                for (int r = 0; r < 4; ++r) o[s][t][r] *= alpha;
        }

        // wave-private LDS round trip (lgkmcnt orders write->read)
        half8 pb[2][2];
#pragma unroll
        for (int s = 0; s < 2; ++s) {
            pb[s][0] = *(const half8*)&Ps[wv][s][id * KP + quad * 8];
            pb[s][1] = *(const half8*)&Ps[wv][s][id * KP + 32 + quad * 8];
        }

        // V A-frags from L2, shared by both strips; O^T += V^T P^T
#pragma unroll
        for (int t = 0; t < 4; ++t) {
            const _Float16* vp = vt + (size_t)(b * NH + 16 * t + id) * NT + kb + quad * 8;
            half8 va0 = *(const half8*)vp;
            half8 va1 = *(const half8*)(vp + 32);
            o[0][t] = __builtin_amdgcn_mfma_f32_16x16x32_f16(va0, pb[0][0], o[0][t], 0, 0, 0);
            o[0][t] = __builtin_amdgcn_mfma_f32_16x16x32_f16(va1, pb[0][1], o[0][t], 0, 0, 0);
            o[1][t] = __builtin_amdgcn_mfma_f32_16x16x32_f16(va0, pb[1][0], o[1][t], 0, 0, 0);
            o[1][t] = __builtin_amdgcn_mfma_f32_16x16x32_f16(va1, pb[1][1], o[1][t], 0, 0, 0);
        }
    }

    // epilogue: normalized O-hat (fp16) + (m, l)
    const int p = b * ITEMS_PB + item;
#pragma unroll
    for (int s = 0; s < 2; ++s) {
        const float rl = 1.f / l_i[s];
#pragma unroll
        for (int t = 0; t < 4; ++t) {
            half4 oh = {(_Float16)(o[s][t][0] * rl), (_Float16)(o[s][t][1] * rl),
                        (_Float16)(o[s][t][2] * rl), (_Float16)(o[s][t][3] * rl)};
            *(half4*)&Opart[(size_t)(p * 32 + s * 16 + id) * NH + 16 * t + quad * 4] = oh;
        }
        if (quad == 0)
            MLpart[p * 32 + s * 16 + id] = make_float2(m_i[s], l_i[s]);
    }
}

// ---------------------------------------------------------------------------
// Kernel 3: combine. Block per (qs, b): 32 rows x 8 col-chunks.
// out = sum_s w_s O-hat_s / sum_s w_s,  w_s = l_s * exp(m_s - M)
// ---------------------------------------------------------------------------
__global__ __launch_bounds__(256) void attn_combine(
    const _Float16* __restrict__ Opart, const float2* __restrict__ MLpart,
    float* __restrict__ out)
{
    const int qs = blockIdx.x, b = blockIdx.y;
    const int tid = threadIdx.x;
    const int row = tid >> 3;              // 0..31
    const int hc  = tid & 7;               // halves hc*8..+7
    const int g = qs >> 3;
    const int nseg = (g + 1 < 8) ? g + 1 : 8;
    int base = (g < 8) ? 4 * g * (g + 1) + (qs - 8 * g) * (g + 1)
                       : 288 + 64 * (g - 8) + (qs - 8 * g) * 8;
    base += b * ITEMS_PB;

    float2 ml[8];
    float M = NEG_BIG;
    for (int s = 0; s < nseg; ++s) {
        ml[s] = MLpart[(base + s) * 32 + row];
        M = fmaxf(M, ml[s].x);
    }
    float W = 0.f, acc[8] = {};
    for (int s = 0; s < nseg; ++s) {
        float w = ml[s].y * __expf(ml[s].x - M);
        W += w;
        half8 oh = *(const half8*)&Opart[(size_t)((base + s) * 32 + row) * NH + hc * 8];
#pragma unroll
        for (int j = 0; j < 8; ++j) acc[j] += w * (float)oh[j];
    }
    const float rl = 1.f / W;
    float* dst = out + (size_t)(b * NT + qs * 32 + row) * NH + hc * 8;
#pragma unroll
    for (int j = 0; j < 8; ++j) dst[j] = acc[j] * rl;
}

extern "C" void kernel_launch(void* const* d_in, const int* in_sizes, int n_in,
                              void* d_out, int out_size, void* d_ws, size_t ws_size,
                              hipStream_t stream) {
    const float* x  = (const float*)d_in[0];
    const float* Wk = (const float*)d_in[1];
    const float* Wq = (const float*)d_in[2];
    const float* Wv = (const float*)d_in[3];

    // ws layout (20.42 MB):
    //   qo/ko/vto fp16: 3 x 2,097,152          = 6,291,456
    //   Wh fp16: 3*64*512*2                    =   196,608
    //   MLpart float2: 3200*32*8               =   819,200
    //   Opart fp16: 3200*32*64*2               = 13,107,200
    char* wsb = (char*)d_ws;
    _Float16* qo    = (_Float16*)wsb;
    _Float16* ko    = qo + 1048576;
    _Float16* vto   = ko + 1048576;
    _Float16* Wh    = vto + 1048576;
    float2*   MLpart= (float2*)(wsb + 6488064);
    _Float16* Opart = (_Float16*)(wsb + 7307264);

    wconv<<<96, 256, 0, stream>>>(Wk, Wq, Wv, Wh);
    qkv_mfma<<<NB * NT / 16, 256, 0, stream>>>(x, Wh, qo, ko, vto);
    attn_part<<<dim3(ITEMS_PB / 4, NB), 256, 0, stream>>>(qo, ko, vto, Opart, MLpart);
    attn_combine<<<dim3(128, NB), 256, 0, stream>>>(Opart, MLpart, (float*)d_out);
}

// Round 7
// 168.009 us; speedup vs baseline: 2.0825x; 1.0287x over previous
//
#include <hip/hip_runtime.h>

typedef unsigned short u16;
typedef unsigned int   u32;

#define NB 4
#define NT 4096
#define NC 512
#define NH 64
// scores scaled by EMBED**-0.5 = 512**-0.5, folded into Wq at convert time
#define ATT_SCALE 0.044194173824159216f
#define NEG_BIG   -30000.0f
#define ITEMS_PB  1088     // attention work items per batch (sum 8m, m=1..16)

typedef __attribute__((ext_vector_type(8))) _Float16 half8;
typedef __attribute__((ext_vector_type(4))) _Float16 half4;
typedef __attribute__((ext_vector_type(4))) float    floatx4;

// ---------------------------------------------------------------------------
// Kernel 0: convert W (fp32) -> Wh (fp16), [w][h][512]; w: 0=q(scaled),1=k,2=v
// ---------------------------------------------------------------------------
__global__ __launch_bounds__(256) void wconv(
    const float* __restrict__ Wk, const float* __restrict__ Wq,
    const float* __restrict__ Wv, _Float16* __restrict__ Wh)
{
    const int gid = blockIdx.x * 256 + threadIdx.x;   // 0..24575, 8192 float4 per W
    const int w = gid >> 13;
    const int i = gid & 8191;
    const float* src = (w == 0) ? Wq : (w == 1) ? Wk : Wv;
    const float sc = (w == 0) ? ATT_SCALE : 1.0f;
    float4 f = *(const float4*)&src[i * 4];
    half4 h = {(_Float16)(f.x * sc), (_Float16)(f.y * sc),
               (_Float16)(f.z * sc), (_Float16)(f.w * sc)};
    *(half4*)&Wh[w * (NH * NC) + i * 4] = h;
}

// ---------------------------------------------------------------------------
// Kernel 1: q/k/v projection GEMM, 4-way k-split. Block = 4 waves over the
// SAME 16 x-rows; wave wv handles k in [wv*128, +128). Partials deposited in
// LDS; epilogue distributed across ALL 4 waves (3 frags each). Grid 1024
// blocks -> 16 waves/CU. No barriers in the k-loop.
// ---------------------------------------------------------------------------
__global__ __launch_bounds__(256) void qkv_mfma(
    const float* __restrict__ x, const _Float16* __restrict__ Wh,
    _Float16* __restrict__ qo, _Float16* __restrict__ ko,
    _Float16* __restrict__ vto)
{
    __shared__ __align__(16) floatx4 red[48][64];     // [frag*4+wv][lane], 48 KB

    const int tid  = threadIdx.x;
    const int wv   = tid >> 6;
    const int lane = tid & 63;
    const int quad = lane >> 4;
    const int id   = lane & 15;
    const int rowbase = blockIdx.x * 16;

    floatx4 acc[3][4] = {};
    const float* xp = x + (size_t)(rowbase + id) * NC + wv * 128;

#pragma unroll
    for (int ks = 0; ks < 4; ++ks) {
        float4 f0 = *(const float4*)&xp[ks * 32 + quad * 8];
        float4 f1 = *(const float4*)&xp[ks * 32 + quad * 8 + 4];
        half8 a;
        a[0] = (_Float16)f0.x; a[1] = (_Float16)f0.y;
        a[2] = (_Float16)f0.z; a[3] = (_Float16)f0.w;
        a[4] = (_Float16)f1.x; a[5] = (_Float16)f1.y;
        a[6] = (_Float16)f1.z; a[7] = (_Float16)f1.w;
#pragma unroll
        for (int w = 0; w < 3; ++w)
#pragma unroll
            for (int nt = 0; nt < 4; ++nt) {
                half8 bf = *(const half8*)&Wh[(w * NH + nt * 16 + id) * NC
                                              + wv * 128 + ks * 32 + quad * 8];
                acc[w][nt] = __builtin_amdgcn_mfma_f32_16x16x32_f16(a, bf, acc[w][nt], 0, 0, 0);
            }
    }

    // deposit all partials
#pragma unroll
    for (int w = 0; w < 3; ++w)
#pragma unroll
        for (int nt = 0; nt < 4; ++nt)
            red[(w * 4 + nt) * 4 + wv][lane] = acc[w][nt];
    __syncthreads();

    // distributed epilogue: wave wv reduces + stores frags [wv*3, wv*3+3)
    const int bb = rowbase >> 12;
    const int t0 = (rowbase & (NT - 1)) + quad * 4;
#pragma unroll
    for (int fi = 0; fi < 3; ++fi) {
        const int f = wv * 3 + fi;
        floatx4 s = red[f * 4 + 0][lane] + red[f * 4 + 1][lane]
                  + red[f * 4 + 2][lane] + red[f * 4 + 3][lane];
        const int w  = f >> 2, nt = f & 3;
        const int h  = nt * 16 + id;
        if (w == 2) {
            half4 vh = {(_Float16)s[0], (_Float16)s[1], (_Float16)s[2], (_Float16)s[3]};
            *(half4*)&vto[(bb * NH + h) * NT + t0] = vh;
        } else {
            _Float16* dst = (w == 0) ? qo : ko;
#pragma unroll
            for (int r = 0; r < 4; ++r)
                dst[(rowbase + quad * 4 + r) * NH + h] = (_Float16)s[r];
        }
    }
}

// ---------------------------------------------------------------------------
// Kernel 2: attention partials — barrier-free, wave-independent flash.
// Each WAVE = one item (b, qs, seg): 32 q-rows (2 strips of 16 sharing every
// K/V fragment) x a slice of <=4 k-tiles. nseg(qs) = (qs>>3)+1 = ceil(ntiles/4)
// (ntiles = qs/2+1), so group m = nseg covers 8 qs values, 8m items, base
// 4m(m-1); total 1088 items/batch. K/V frags straight from L2 (no K/V LDS,
// no __syncthreads); P via wave-private LDS. Emits normalized O-hat + (m,l).
// ---------------------------------------------------------------------------
__global__ __launch_bounds__(256) void attn_part(
    const _Float16* __restrict__ q, const _Float16* __restrict__ k,
    const _Float16* __restrict__ vt, _Float16* __restrict__ Opart,
    float2* __restrict__ MLpart)
{
    constexpr int KP = 72;
    __shared__ __align__(16) _Float16 Ps[4][2][16 * KP];   // 18.4 KB

    const int tid  = threadIdx.x;
    const int wv   = tid >> 6;
    const int lane = tid & 63;
    const int quad = lane >> 4;
    const int id   = lane & 15;
    const int item = blockIdx.x * 4 + wv;      // [0, 1088)
    const int b    = blockIdx.y;

    // decode item -> (qs, seg): group m starts at 4m(m-1), has 8m items
    int m = (int)((1.0f + __builtin_sqrtf((float)item + 1.0f)) * 0.5f);
    while (4 * m * (m + 1) <= item) ++m;
    while (m > 1 && 4 * m * (m - 1) > item) --m;
    const int rem  = item - 4 * m * (m - 1);
    const int qs   = 8 * (m - 1) + rem / m;
    const int seg  = rem - (rem / m) * m;
    const int ntiles = (qs >> 1) + 1;          // causal k-tiles for this 32-row strip
    const int t0 = seg * ntiles / m;
    const int t1 = (seg + 1) * ntiles / m;     // 3..4 tiles per item

    // Q B-frags for both strips (q pre-scaled by ATT_SCALE)
    half8 qb[2][2];
#pragma unroll
    for (int s = 0; s < 2; ++s) {
        const _Float16* qp = q + (size_t)(b * NT + qs * 32 + s * 16 + id) * NH + quad * 8;
        qb[s][0] = *(const half8*)qp;
        qb[s][1] = *(const half8*)(qp + 32);
    }

    floatx4 o[2][4] = {};
    float m_i[2] = {NEG_BIG, NEG_BIG}, l_i[2] = {0.f, 0.f};

    for (int kt = t0; kt < t1; ++kt) {
        const int kb = kt * 64;

        // K A-frags straight from L2: 8 x half8 (16 B/lane, coalesced)
        half8 ka[4][2];
#pragma unroll
        for (int t = 0; t < 4; ++t) {
            const _Float16* kp = k + (size_t)(b * NT + kb + 16 * t + id) * NH + quad * 8;
            ka[t][0] = *(const half8*)kp;
            ka[t][1] = *(const half8*)(kp + 32);
        }

        // S^T[64k x 16q] per strip — K frags shared by both strips
        floatx4 s4[2][4] = {};
#pragma unroll
        for (int t = 0; t < 4; ++t)
#pragma unroll
            for (int h2 = 0; h2 < 2; ++h2) {
                s4[0][t] = __builtin_amdgcn_mfma_f32_16x16x32_f16(ka[t][h2], qb[0][h2], s4[0][t], 0, 0, 0);
                s4[1][t] = __builtin_amdgcn_mfma_f32_16x16x32_f16(ka[t][h2], qb[1][h2], s4[1][t], 0, 0, 0);
            }

        if (kt == ntiles - 1) {                // diagonal tile: causal mask
#pragma unroll
            for (int s = 0; s < 2; ++s) {
                const int qrow = qs * 32 + s * 16 + id;
#pragma unroll
                for (int t = 0; t < 4; ++t)
#pragma unroll
                    for (int r = 0; r < 4; ++r)
                        if (kb + 16 * t + quad * 4 + r > qrow)
                            s4[s][t][r] = NEG_BIG;
            }
        }

        // online softmax per strip: in-lane(16) + 2 shuffles
#pragma unroll
        for (int s = 0; s < 2; ++s) {
            float mx = s4[s][0][0];
#pragma unroll
            for (int t = 0; t < 4; ++t)
#pragma unroll
                for (int r = 0; r < 4; ++r) mx = fmaxf(mx, s4[s][t][r]);
            mx = fmaxf(mx, __shfl_xor(mx, 16));
            mx = fmaxf(mx, __shfl_xor(mx, 32));
            float mnew  = fmaxf(m_i[s], mx);
            float alpha = __expf(m_i[s] - mnew);
            m_i[s] = mnew;
            float psum = 0.f;
#pragma unroll
            for (int t = 0; t < 4; ++t)
#pragma unroll
                for (int r = 0; r < 4; ++r) {
                    float p = __expf(s4[s][t][r] - mnew);
                    s4[s][t][r] = p;
                    psum += p;
                }
            psum += __shfl_xor(psum, 16);
            psum += __shfl_xor(psum, 32);
            l_i[s] = l_i[s] * alpha + psum;

            // spill P[q=id][k] (packed b64), rescale O
#pragma unroll
            for (int t = 0; t < 4; ++t) {
                half4 ph = {(_Float16)s4[s][t][0], (_Float16)s4[s][t][1],
                            (_Float16)s4[s][t][2], (_Float16)s4[s][t][3]};
                *(half4*)&Ps[wv][s][id * KP + 16 * t + quad * 4] = ph;
            }
#pragma unroll
            for (int t = 0; t < 4; ++t)
#pragma unroll
                for (int r = 0; r < 4; ++r) o[s][t][r] *= alpha;
        }

        // wave-private LDS round trip (lgkmcnt orders write->read)
        half8 pb[2][2];
#pragma unroll
        for (int s = 0; s < 2; ++s) {
            pb[s][0] = *(const half8*)&Ps[wv][s][id * KP + quad * 8];
            pb[s][1] = *(const half8*)&Ps[wv][s][id * KP + 32 + quad * 8];
        }

        // V A-frags from L2, shared by both strips; O^T += V^T P^T
#pragma unroll
        for (int t = 0; t < 4; ++t) {
            const _Float16* vp = vt + (size_t)(b * NH + 16 * t + id) * NT + kb + quad * 8;
            half8 va0 = *(const half8*)vp;
            half8 va1 = *(const half8*)(vp + 32);
            o[0][t] = __builtin_amdgcn_mfma_f32_16x16x32_f16(va0, pb[0][0], o[0][t], 0, 0, 0);
            o[0][t] = __builtin_amdgcn_mfma_f32_16x16x32_f16(va1, pb[0][1], o[0][t], 0, 0, 0);
            o[1][t] = __builtin_amdgcn_mfma_f32_16x16x32_f16(va0, pb[1][0], o[1][t], 0, 0, 0);
            o[1][t] = __builtin_amdgcn_mfma_f32_16x16x32_f16(va1, pb[1][1], o[1][t], 0, 0, 0);
        }
    }

    // epilogue: normalized O-hat (fp16) + (m, l)
    const int p = b * ITEMS_PB + item;
#pragma unroll
    for (int s = 0; s < 2; ++s) {
        const float rl = 1.f / l_i[s];
#pragma unroll
        for (int t = 0; t < 4; ++t) {
            half4 oh = {(_Float16)(o[s][t][0] * rl), (_Float16)(o[s][t][1] * rl),
                        (_Float16)(o[s][t][2] * rl), (_Float16)(o[s][t][3] * rl)};
            *(half4*)&Opart[(size_t)(p * 32 + s * 16 + id) * NH + 16 * t + quad * 4] = oh;
        }
        if (quad == 0)
            MLpart[p * 32 + s * 16 + id] = make_float2(m_i[s], l_i[s]);
    }
}

// ---------------------------------------------------------------------------
// Kernel 3: combine. Block per (qs, b): 32 rows x 8 col-chunks.
// out = sum_s w_s O-hat_s / sum_s w_s,  w_s = l_s * exp(m_s - M)
// ---------------------------------------------------------------------------
__global__ __launch_bounds__(256) void attn_combine(
    const _Float16* __restrict__ Opart, const float2* __restrict__ MLpart,
    float* __restrict__ out)
{
    const int qs = blockIdx.x, b = blockIdx.y;
    const int tid = threadIdx.x;
    const int row = tid >> 3;              // 0..31
    const int hc  = tid & 7;               // halves hc*8..+7
    const int m = (qs >> 3) + 1;           // nseg for this qs
    int base = 4 * m * (m - 1) + (qs - 8 * (m - 1)) * m + b * ITEMS_PB;

    float2 ml[16];
    float M = NEG_BIG;
    for (int s = 0; s < m; ++s) {
        ml[s] = MLpart[(base + s) * 32 + row];
        M = fmaxf(M, ml[s].x);
    }
    float W = 0.f, acc[8] = {};
    for (int s = 0; s < m; ++s) {
        float w = ml[s].y * __expf(ml[s].x - M);
        W += w;
        half8 oh = *(const half8*)&Opart[(size_t)((base + s) * 32 + row) * NH + hc * 8];
#pragma unroll
        for (int j = 0; j < 8; ++j) acc[j] += w * (float)oh[j];
    }
    const float rl = 1.f / W;
    float* dst = out + (size_t)(b * NT + qs * 32 + row) * NH + hc * 8;
#pragma unroll
    for (int j = 0; j < 8; ++j) dst[j] = acc[j] * rl;
}

extern "C" void kernel_launch(void* const* d_in, const int* in_sizes, int n_in,
                              void* d_out, int out_size, void* d_ws, size_t ws_size,
                              hipStream_t stream) {
    const float* x  = (const float*)d_in[0];
    const float* Wk = (const float*)d_in[1];
    const float* Wq = (const float*)d_in[2];
    const float* Wv = (const float*)d_in[3];

    // ws layout (25.43 MB):
    //   qo/ko/vto fp16: 3 x 2,097,152          = 6,291,456
    //   Wh fp16: 3*64*512*2                    =   196,608
    //   MLpart float2: 4*1088*32*8             = 1,114,112
    //   Opart fp16: 4*1088*32*64*2             = 17,825,792
    char* wsb = (char*)d_ws;
    _Float16* qo    = (_Float16*)wsb;
    _Float16* ko    = qo + 1048576;
    _Float16* vto   = ko + 1048576;
    _Float16* Wh    = vto + 1048576;
    float2*   MLpart= (float2*)(wsb + 6488064);
    _Float16* Opart = (_Float16*)(wsb + 7602176);

    wconv<<<96, 256, 0, stream>>>(Wk, Wq, Wv, Wh);
    qkv_mfma<<<NB * NT / 16, 256, 0, stream>>>(x, Wh, qo, ko, vto);
    attn_part<<<dim3(ITEMS_PB / 4, NB), 256, 0, stream>>>(qo, ko, vto, Opart, MLpart);
    attn_combine<<<dim3(128, NB), 256, 0, stream>>>(Opart, MLpart, (float*)d_out);
}

// Round 8
// 159.556 us; speedup vs baseline: 2.1928x; 1.0530x over previous
//
#include <hip/hip_runtime.h>

typedef unsigned short u16;
typedef unsigned int   u32;

#define NB 4
#define NT 4096
#define NC 512
#define NH 64
#define ATT_SCALE 0.044194173824159216f
#define NEG_BIG   -30000.0f
#define ITEMS_PB  1088     // attention work items per batch (sum 8m, m=1..16)

typedef __attribute__((ext_vector_type(8))) _Float16 half8;
typedef __attribute__((ext_vector_type(4))) _Float16 half4;
typedef __attribute__((ext_vector_type(4))) float    floatx4;

// Fragment-layout addressing: all MFMA operands live in 1KB blocks of 512
// halves; element (id, q4, j) at id*32 + q4*8 + j. A wave load for one
// operand is lane-offset id*32+quad*8 (halves) = one contiguous 1KB burst.

// ---------------------------------------------------------------------------
// Kernel 0: W (fp32) -> Wh' fragment layout [w][ks16][nt4]{1KB blocks};
// w: 0=q(ATT_SCALE folded), 1=k, 2=v. Value W[h][c] -> block ((w*16+ks)*4+nt),
// id=h&15 (nt=h>>4), q4=(c>>3)&3, j=c&7, ks=c>>5.
// ---------------------------------------------------------------------------
__global__ __launch_bounds__(256) void wconv(
    const float* __restrict__ Wk, const float* __restrict__ Wq,
    const float* __restrict__ Wv, _Float16* __restrict__ Wh)
{
    const int gid = blockIdx.x * 256 + threadIdx.x;   // 24576 float4s
    const int w = gid >> 13;
    const int i = gid & 8191;                         // float4 within 64x512
    const int h = i >> 7, c = (i & 127) * 4;
    const float* src = (w == 0) ? Wq : (w == 1) ? Wk : Wv;
    const float sc = (w == 0) ? ATT_SCALE : 1.0f;
    float4 f = *(const float4*)&src[h * NC + c];
    half4 o = {(_Float16)(f.x * sc), (_Float16)(f.y * sc),
               (_Float16)(f.z * sc), (_Float16)(f.w * sc)};
    const int blk = ((w * 16 + (c >> 5)) * 4 + (h >> 4));
    *(half4*)&Wh[(size_t)blk * 512 + (h & 15) * 32 + ((c >> 3) & 3) * 8 + (c & 7)] = o;
}

// ---------------------------------------------------------------------------
// Kernel 1: q/k/v projection GEMM, 2-way k-split. Block = 256 thr = 4 waves
// (rg 0-1 x kh 0-1); wave (rg,kh) does 16 rows x 256 k-cols, 8 ks-steps x
// 12 MFMA. kh=1 partials through 24KB LDS; kh=0 reduces + writes Q'/K'/V'
// fragment layouts. Grid 512 blocks = 2048 waves.
// Q': [b][q16 256][hop2]{1KB}   K': [b][kt64][t4][hop2]{1KB}
// V': [b][kt64][th4][kop2]{1KB}
// ---------------------------------------------------------------------------
__global__ __launch_bounds__(256) void qkv_mfma(
    const float* __restrict__ x, const _Float16* __restrict__ Wh,
    _Float16* __restrict__ Qf, _Float16* __restrict__ Kf,
    _Float16* __restrict__ Vf)
{
    __shared__ __align__(16) floatx4 red[2][12][64];  // 24 KB

    const int tid  = threadIdx.x;
    const int wv   = tid >> 6;
    const int lane = tid & 63;
    const int quad = lane >> 4;
    const int id   = lane & 15;
    const int rg   = wv >> 1, kh = wv & 1;
    const int rowbase = blockIdx.x * 32 + rg * 16;

    floatx4 acc[3][4] = {};
    const float* xp = x + (size_t)(rowbase + id) * NC + kh * 256;
    const int loff = id * 32 + quad * 8;              // frag lane offset (halves)

#pragma unroll
    for (int ks = 0; ks < 8; ++ks) {
        float4 f0 = *(const float4*)&xp[ks * 32 + quad * 8];
        float4 f1 = *(const float4*)&xp[ks * 32 + quad * 8 + 4];
        half8 a;
        a[0] = (_Float16)f0.x; a[1] = (_Float16)f0.y;
        a[2] = (_Float16)f0.z; a[3] = (_Float16)f0.w;
        a[4] = (_Float16)f1.x; a[5] = (_Float16)f1.y;
        a[6] = (_Float16)f1.z; a[7] = (_Float16)f1.w;
        const int ksg = kh * 8 + ks;
#pragma unroll
        for (int w = 0; w < 3; ++w)
#pragma unroll
            for (int nt = 0; nt < 4; ++nt) {
                half8 bf = *(const half8*)&Wh[(size_t)((w * 16 + ksg) * 4 + nt) * 512 + loff];
                acc[w][nt] = __builtin_amdgcn_mfma_f32_16x16x32_f16(a, bf, acc[w][nt], 0, 0, 0);
            }
    }

    if (kh == 1) {
#pragma unroll
        for (int w = 0; w < 3; ++w)
#pragma unroll
            for (int nt = 0; nt < 4; ++nt)
                red[rg][w * 4 + nt][lane] = acc[w][nt];
    }
    __syncthreads();
    if (kh == 1) return;

#pragma unroll
    for (int w = 0; w < 3; ++w)
#pragma unroll
        for (int nt = 0; nt < 4; ++nt)
            acc[w][nt] += red[rg][w * 4 + nt][lane];

    // epilogue: C-frag (row=quad*4+r, h=nt*16+id) -> fragment layouts
    const int b  = rowbase >> 12, L = rowbase & 4095;
    const int q16 = L >> 4, kt = L >> 6, tt = (L >> 4) & 3;
    const int kop = ((rowbase & 63) + quad * 4) >> 5;
    const int q4k = ((((rowbase & 63) + quad * 4) >> 3) & 3);
#pragma unroll
    for (int nt = 0; nt < 4; ++nt) {
        const int hop = nt >> 1;
        const int q4h = (nt * 2 + (id >> 3)) & 3;
        const int j   = id & 7;
        const size_t qa = (size_t)((b * 256 + q16) * 2 + hop) * 512 + q4h * 8 + j;
        const size_t ka = (size_t)(((b * 64 + kt) * 4 + tt) * 2 + hop) * 512 + q4h * 8 + j;
#pragma unroll
        for (int r = 0; r < 4; ++r) {
            Qf[qa + (quad * 4 + r) * 32] = (_Float16)acc[0][nt][r];
            Kf[ka + (quad * 4 + r) * 32] = (_Float16)acc[1][nt][r];
        }
        half4 vh = {(_Float16)acc[2][nt][0], (_Float16)acc[2][nt][1],
                    (_Float16)acc[2][nt][2], (_Float16)acc[2][nt][3]};
        const size_t va = (size_t)(((b * 64 + kt) * 4 + nt) * 2 + kop) * 512
                        + id * 32 + q4k * 8 + (quad & 1) * 4;
        *(half4*)&Vf[va] = vh;
    }
}

// ---------------------------------------------------------------------------
// Kernel 2: attention partials — 8 independent wave-items per 512-thr block
// (forced co-residency). Item (b, qs, seg): 32 q-rows x <=4 k-tiles.
// All operand loads are contiguous-1KB fragment loads. Transposed flash
// (S^T = K Q^T, O^T = V^T P^T), per-lane softmax, P via wave-private LDS.
// ---------------------------------------------------------------------------
__global__ __launch_bounds__(512, 4) void attn_part(
    const _Float16* __restrict__ Qf, const _Float16* __restrict__ Kf,
    const _Float16* __restrict__ Vf, _Float16* __restrict__ Opart,
    float2* __restrict__ MLpart)
{
    constexpr int KP = 72;
    __shared__ __align__(16) _Float16 Ps[8][2][16 * KP];   // 36.9 KB

    const int tid  = threadIdx.x;
    const int wv   = tid >> 6;
    const int lane = tid & 63;
    const int quad = lane >> 4;
    const int id   = lane & 15;
    const int item = blockIdx.x * 8 + wv;      // [0, 1088)
    const int b    = blockIdx.y;
    const int loff = id * 32 + quad * 8;       // frag lane offset (halves)

    // decode item -> (qs, seg): group m starts at 4m(m-1), has 8m items
    int m = (int)((1.0f + __builtin_sqrtf((float)item + 1.0f)) * 0.5f);
    while (4 * m * (m + 1) <= item) ++m;
    while (m > 1 && 4 * m * (m - 1) > item) --m;
    const int rem  = item - 4 * m * (m - 1);
    const int qs   = 8 * (m - 1) + rem / m;
    const int seg  = rem - (rem / m) * m;
    const int ntiles = (qs >> 1) + 1;
    const int t0 = seg * ntiles / m;
    const int t1 = (seg + 1) * ntiles / m;

    // Q fragments (pre-scaled): 2 strips x 2 h-halves
    half8 qb[2][2];
#pragma unroll
    for (int s = 0; s < 2; ++s) {
        const size_t qa = (size_t)((b * 256 + qs * 2 + s) * 2) * 512 + loff;
        qb[s][0] = *(const half8*)&Qf[qa];
        qb[s][1] = *(const half8*)&Qf[qa + 512];
    }

    floatx4 o[2][4] = {};
    float m_i[2] = {NEG_BIG, NEG_BIG}, l_i[2] = {0.f, 0.f};

    for (int kt = t0; kt < t1; ++kt) {
        const size_t tb = (size_t)((b * 64 + kt) * 4) * 2 * 512;  // tile base (halves)

        // S^T: A = K frags (1KB loads), B = Q frags
        floatx4 s4[2][4] = {};
#pragma unroll
        for (int t = 0; t < 4; ++t) {
            half8 ka0 = *(const half8*)&Kf[tb + (size_t)t * 1024 + loff];
            half8 ka1 = *(const half8*)&Kf[tb + (size_t)t * 1024 + 512 + loff];
            s4[0][t] = __builtin_amdgcn_mfma_f32_16x16x32_f16(ka0, qb[0][0], s4[0][t], 0, 0, 0);
            s4[0][t] = __builtin_amdgcn_mfma_f32_16x16x32_f16(ka1, qb[0][1], s4[0][t], 0, 0, 0);
            s4[1][t] = __builtin_amdgcn_mfma_f32_16x16x32_f16(ka0, qb[1][0], s4[1][t], 0, 0, 0);
            s4[1][t] = __builtin_amdgcn_mfma_f32_16x16x32_f16(ka1, qb[1][1], s4[1][t], 0, 0, 0);
        }

        // half-hoist V loads (t=0,1) to overlap softmax latency
        half8 va[4][2];
#pragma unroll
        for (int t = 0; t < 2; ++t) {
            va[t][0] = *(const half8*)&Vf[tb + (size_t)t * 1024 + loff];
            va[t][1] = *(const half8*)&Vf[tb + (size_t)t * 1024 + 512 + loff];
        }

        if (kt == ntiles - 1) {                // diagonal tile: causal mask
            const int kb = kt * 64;
#pragma unroll
            for (int s = 0; s < 2; ++s) {
                const int qrow = qs * 32 + s * 16 + id;
#pragma unroll
                for (int t = 0; t < 4; ++t)
#pragma unroll
                    for (int r = 0; r < 4; ++r)
                        if (kb + 16 * t + quad * 4 + r > qrow)
                            s4[s][t][r] = NEG_BIG;
            }
        }

        // online softmax per strip: in-lane(16) + 2 shuffles
#pragma unroll
        for (int s = 0; s < 2; ++s) {
            float mx = s4[s][0][0];
#pragma unroll
            for (int t = 0; t < 4; ++t)
#pragma unroll
                for (int r = 0; r < 4; ++r) mx = fmaxf(mx, s4[s][t][r]);
            mx = fmaxf(mx, __shfl_xor(mx, 16));
            mx = fmaxf(mx, __shfl_xor(mx, 32));
            float mnew  = fmaxf(m_i[s], mx);
            float alpha = __expf(m_i[s] - mnew);
            m_i[s] = mnew;
            float psum = 0.f;
#pragma unroll
            for (int t = 0; t < 4; ++t)
#pragma unroll
                for (int r = 0; r < 4; ++r) {
                    float p = __expf(s4[s][t][r] - mnew);
                    s4[s][t][r] = p;
                    psum += p;
                }
            psum += __shfl_xor(psum, 16);
            psum += __shfl_xor(psum, 32);
            l_i[s] = l_i[s] * alpha + psum;

#pragma unroll
            for (int t = 0; t < 4; ++t) {
                half4 ph = {(_Float16)s4[s][t][0], (_Float16)s4[s][t][1],
                            (_Float16)s4[s][t][2], (_Float16)s4[s][t][3]};
                *(half4*)&Ps[wv][s][id * KP + 16 * t + quad * 4] = ph;
            }
#pragma unroll
            for (int t = 0; t < 4; ++t)
#pragma unroll
                for (int r = 0; r < 4; ++r) o[s][t][r] *= alpha;
        }

        // wave-private LDS round trip (lgkmcnt orders write->read)
        half8 pb[2][2];
#pragma unroll
        for (int s = 0; s < 2; ++s) {
            pb[s][0] = *(const half8*)&Ps[wv][s][id * KP + quad * 8];
            pb[s][1] = *(const half8*)&Ps[wv][s][id * KP + 32 + quad * 8];
        }

        // remaining V loads, then O^T += V^T P^T
#pragma unroll
        for (int t = 2; t < 4; ++t) {
            va[t][0] = *(const half8*)&Vf[tb + (size_t)t * 1024 + loff];
            va[t][1] = *(const half8*)&Vf[tb + (size_t)t * 1024 + 512 + loff];
        }
#pragma unroll
        for (int t = 0; t < 4; ++t) {
            o[0][t] = __builtin_amdgcn_mfma_f32_16x16x32_f16(va[t][0], pb[0][0], o[0][t], 0, 0, 0);
            o[0][t] = __builtin_amdgcn_mfma_f32_16x16x32_f16(va[t][1], pb[0][1], o[0][t], 0, 0, 0);
            o[1][t] = __builtin_amdgcn_mfma_f32_16x16x32_f16(va[t][0], pb[1][0], o[1][t], 0, 0, 0);
            o[1][t] = __builtin_amdgcn_mfma_f32_16x16x32_f16(va[t][1], pb[1][1], o[1][t], 0, 0, 0);
        }
    }

    // epilogue: normalized O-hat (fp16) + (m, l)
    const int p = b * ITEMS_PB + item;
#pragma unroll
    for (int s = 0; s < 2; ++s) {
        const float rl = 1.f / l_i[s];
#pragma unroll
        for (int t = 0; t < 4; ++t) {
            half4 oh = {(_Float16)(o[s][t][0] * rl), (_Float16)(o[s][t][1] * rl),
                        (_Float16)(o[s][t][2] * rl), (_Float16)(o[s][t][3] * rl)};
            *(half4*)&Opart[(size_t)(p * 32 + s * 16 + id) * NH + 16 * t + quad * 4] = oh;
        }
        if (quad == 0)
            MLpart[p * 32 + s * 16 + id] = make_float2(m_i[s], l_i[s]);
    }
}

// ---------------------------------------------------------------------------
// Kernel 3: combine. Block per (qs, b): 32 rows x 8 col-chunks.
// ---------------------------------------------------------------------------
__global__ __launch_bounds__(256) void attn_combine(
    const _Float16* __restrict__ Opart, const float2* __restrict__ MLpart,
    float* __restrict__ out)
{
    const int qs = blockIdx.x, b = blockIdx.y;
    const int tid = threadIdx.x;
    const int row = tid >> 3;
    const int hc  = tid & 7;
    const int m = (qs >> 3) + 1;
    int base = 4 * m * (m - 1) + (qs - 8 * (m - 1)) * m + b * ITEMS_PB;

    float2 ml[16];
    float M = NEG_BIG;
    for (int s = 0; s < m; ++s) {
        ml[s] = MLpart[(base + s) * 32 + row];
        M = fmaxf(M, ml[s].x);
    }
    float W = 0.f, acc[8] = {};
    for (int s = 0; s < m; ++s) {
        float w = ml[s].y * __expf(ml[s].x - M);
        W += w;
        half8 oh = *(const half8*)&Opart[(size_t)((base + s) * 32 + row) * NH + hc * 8];
#pragma unroll
        for (int j = 0; j < 8; ++j) acc[j] += w * (float)oh[j];
    }
    const float rl = 1.f / W;
    float* dst = out + (size_t)(b * NT + qs * 32 + row) * NH + hc * 8;
#pragma unroll
    for (int j = 0; j < 8; ++j) dst[j] = acc[j] * rl;
}

extern "C" void kernel_launch(void* const* d_in, const int* in_sizes, int n_in,
                              void* d_out, int out_size, void* d_ws, size_t ws_size,
                              hipStream_t stream) {
    const float* x  = (const float*)d_in[0];
    const float* Wk = (const float*)d_in[1];
    const float* Wq = (const float*)d_in[2];
    const float* Wv = (const float*)d_in[3];

    // ws layout (25.43 MB): Qf/Kf/Vf 3x2MB | Wh 192KB | ML 1.06MB | Opart 17MB
    char* wsb = (char*)d_ws;
    _Float16* Qf    = (_Float16*)wsb;
    _Float16* Kf    = Qf + 1048576;
    _Float16* Vf    = Kf + 1048576;
    _Float16* Wh    = Vf + 1048576;
    float2*   MLpart= (float2*)(wsb + 6488064);
    _Float16* Opart = (_Float16*)(wsb + 7602176);

    wconv<<<96, 256, 0, stream>>>(Wk, Wq, Wv, Wh);
    qkv_mfma<<<512, 256, 0, stream>>>(x, Wh, Qf, Kf, Vf);
    attn_part<<<dim3(ITEMS_PB / 8, NB), 512, 0, stream>>>(Qf, Kf, Vf, Opart, MLpart);
    attn_combine<<<dim3(128, NB), 256, 0, stream>>>(Opart, MLpart, (float*)d_out);
}